// Round 1
// baseline (1809.098 us; speedup 1.0000x reference)
//
#include <hip/hip_runtime.h>

#define N_NODES 20000
#define N_REL 32
#define HID 128
#define EMB 16
#define N_EDGES 600000

// ---- Phase 0: per-(dst,relation) counts -> inverse ----
__global__ void count_k(const int* __restrict__ dst, const int* __restrict__ et,
                        float* __restrict__ counts) {
    int e = blockIdx.x * 256 + threadIdx.x;
    if (e < N_EDGES) atomicAdd(&counts[dst[e] * N_REL + et[e]], 1.0f);
}

__global__ void inv_k(float* __restrict__ counts) {
    int i = blockIdx.x * 256 + threadIdx.x;
    if (i < N_NODES * N_REL) {
        float c = counts[i];
        counts[i] = c > 0.0f ? 1.0f / c : 0.0f;
    }
}

// ---- Layer 1: h1 = b1 + x @ root1  (then edges atomically add messages) ----
__global__ void l1_init_k(const float* __restrict__ x, const float* __restrict__ root1,
                          const float* __restrict__ b1, float* __restrict__ h1) {
    int idx = blockIdx.x * 256 + threadIdx.x;
    if (idx >= N_NODES * HID) return;
    int n = idx >> 7, j = idx & 127;
    float acc = b1[j];
    const float* xs = x + n * EMB;
#pragma unroll
    for (int f = 0; f < EMB; ++f) acc += xs[f] * root1[f * HID + j];
    h1[idx] = acc;
}

__global__ void l1_edge_k(const int* __restrict__ src, const int* __restrict__ dst,
                          const int* __restrict__ et, const float* __restrict__ inv,
                          const float* __restrict__ x, const float* __restrict__ W1,
                          float* __restrict__ h1) {
    long long idx = (long long)blockIdx.x * 256 + threadIdx.x;
    if (idx >= (long long)N_EDGES * HID) return;
    int e = (int)(idx >> 7), j = (int)(idx & 127);
    int s = src[e], d = dst[e], r = et[e];
    float iv = inv[d * N_REL + r];
    const float* xs = x + s * EMB;
    const float* w = W1 + r * EMB * HID + j;
    float acc = 0.0f;
#pragma unroll
    for (int f = 0; f < EMB; ++f) acc += xs[f] * w[f * HID];
    atomicAdd(&h1[d * HID + j], acc * iv);
}

// ---- Layer 2: out = b2 + relu(h1) @ root2  (relu fused at read) ----
__global__ void l2_init_k(const float* __restrict__ h1, const float* __restrict__ root2,
                          const float* __restrict__ b2, float* __restrict__ out) {
    int n = blockIdx.x;
    int j = threadIdx.x;
    __shared__ float hs[HID];
    float v = h1[n * HID + j];
    hs[j] = v > 0.0f ? v : 0.0f;
    __syncthreads();
    float acc = b2[j];
#pragma unroll 8
    for (int k = 0; k < HID; ++k) acc += hs[k] * root2[k * HID + j];
    out[n * HID + j] = acc;
}

__global__ void l2_edge_k(const int* __restrict__ src, const int* __restrict__ dst,
                          const int* __restrict__ et, const float* __restrict__ inv,
                          const float* __restrict__ h1, const float* __restrict__ W2,
                          float* __restrict__ out) {
    int e = blockIdx.x;
    int j = threadIdx.x;
    __shared__ float hs[HID];
    int s = src[e], d = dst[e], r = et[e];
    float v = h1[s * HID + j];
    hs[j] = v > 0.0f ? v : 0.0f;
    __syncthreads();
    float iv = inv[d * N_REL + r];
    const float* w = W2 + r * HID * HID + j;
    float acc = 0.0f;
#pragma unroll 8
    for (int k = 0; k < HID; ++k) acc += hs[k] * w[k * HID];
    atomicAdd(&out[d * HID + j], acc * iv);
}

extern "C" void kernel_launch(void* const* d_in, const int* in_sizes, int n_in,
                              void* d_out, int out_size, void* d_ws, size_t ws_size,
                              hipStream_t stream) {
    const int*   ei    = (const int*)d_in[0];   // [2, E]
    const int*   et    = (const int*)d_in[1];   // [E]
    const float* x     = (const float*)d_in[2]; // [N, 16]
    const float* W1    = (const float*)d_in[3]; // [32, 16, 128]
    const float* root1 = (const float*)d_in[4]; // [16, 128]
    const float* b1    = (const float*)d_in[5]; // [128]
    const float* W2    = (const float*)d_in[6]; // [32, 128, 128]
    const float* root2 = (const float*)d_in[7]; // [128, 128]
    const float* b2    = (const float*)d_in[8]; // [128]
    float* out = (float*)d_out;

    // workspace: counts/inv [N*R] floats, then h1 [N*HID] floats  (12.8 MB total)
    float* counts = (float*)d_ws;
    float* h1     = counts + (size_t)N_NODES * N_REL;

    const int* src = ei;
    const int* dst = ei + N_EDGES;

    hipMemsetAsync(counts, 0, (size_t)N_NODES * N_REL * sizeof(float), stream);
    count_k<<<(N_EDGES + 255) / 256, 256, 0, stream>>>(dst, et, counts);
    inv_k<<<(N_NODES * N_REL + 255) / 256, 256, 0, stream>>>(counts);

    // layer 1
    l1_init_k<<<(N_NODES * HID + 255) / 256, 256, 0, stream>>>(x, root1, b1, h1);
    long long l1_threads = (long long)N_EDGES * HID;
    l1_edge_k<<<(int)((l1_threads + 255) / 256), 256, 0, stream>>>(src, dst, et, counts, x, W1, h1);

    // layer 2 (relu fused into reads of h1)
    l2_init_k<<<N_NODES, HID, 0, stream>>>(h1, root2, b2, out);
    l2_edge_k<<<N_EDGES, HID, 0, stream>>>(src, dst, et, counts, h1, W2, out);
}

// Round 2
// 1083.681 us; speedup vs baseline: 1.6694x; 1.6694x over previous
//
#include <hip/hip_runtime.h>

#define N_NODES 20000
#define N_REL 32
#define HID 128
#define EMB 16
#define N_EDGES 600000
#define C1 64   // chunks per relation, layer-1 edge kernel
#define C2 48   // chunks per relation, layer-2 edge kernel

// ---- Phase 0a: per-(dst,relation) counts + per-relation histogram ----
__global__ void count_k(const int* __restrict__ dst, const int* __restrict__ et,
                        float* __restrict__ counts, int* __restrict__ rel_count) {
    __shared__ int lh[N_REL];
    int t = threadIdx.x;
    if (t < N_REL) lh[t] = 0;
    __syncthreads();
    int e = blockIdx.x * 256 + t;
    if (e < N_EDGES) {
        int r = et[e];
        atomicAdd(&counts[dst[e] * N_REL + r], 1.0f);
        atomicAdd(&lh[r], 1);
    }
    __syncthreads();
    if (t < N_REL && lh[t] > 0) atomicAdd(&rel_count[t], lh[t]);
}

__global__ void inv_k(float* __restrict__ counts) {
    int i = blockIdx.x * 256 + threadIdx.x;
    if (i < N_NODES * N_REL) {
        float c = counts[i];
        counts[i] = c > 0.0f ? 1.0f / c : 0.0f;
    }
}

// ---- Phase 0b: exclusive scan over 32 relations ----
__global__ void scan_k(const int* __restrict__ rel_count, int* __restrict__ rel_off,
                       int* __restrict__ cursors) {
    if (threadIdx.x == 0) {
        int s = 0;
        for (int r = 0; r < N_REL; ++r) {
            rel_off[r] = s;
            cursors[r] = s;
            s += rel_count[r];
        }
        rel_off[N_REL] = s;
    }
}

// ---- Phase 0c: scatter edge ids into relation-sorted perm ----
__global__ void scatter_k(const int* __restrict__ et, int* __restrict__ cursors,
                          int* __restrict__ perm) {
    __shared__ int lh[N_REL];
    __shared__ int lbase[N_REL];
    int t = threadIdx.x;
    if (t < N_REL) lh[t] = 0;
    __syncthreads();
    int e = blockIdx.x * 256 + t;
    int r = -1, my = 0;
    if (e < N_EDGES) { r = et[e]; my = atomicAdd(&lh[r], 1); }
    __syncthreads();
    if (t < N_REL && lh[t] > 0) lbase[t] = atomicAdd(&cursors[t], lh[t]);
    __syncthreads();
    if (e < N_EDGES) perm[lbase[r] + my] = e;
}

// ---- Layer 1 init: h1 = b1 + x @ root1 ----
__global__ void l1_init_k(const float* __restrict__ x, const float* __restrict__ root1,
                          const float* __restrict__ b1, float* __restrict__ h1) {
    int idx = blockIdx.x * 256 + threadIdx.x;
    if (idx >= N_NODES * HID) return;
    int n = idx >> 7, j = idx & 127;
    float acc = b1[j];
    const float* xs = x + n * EMB;
#pragma unroll
    for (int f = 0; f < EMB; ++f) acc += xs[f] * root1[f * HID + j];
    h1[idx] = acc;
}

// ---- Layer 1 edges: relation-chunked, weights in registers, no LDS ----
__global__ __launch_bounds__(128) void l1_rel_k(
    const int* __restrict__ perm, const int* __restrict__ rel_off,
    const int* __restrict__ src, const int* __restrict__ dst,
    const float* __restrict__ inv, const float* __restrict__ x,
    const float* __restrict__ W1, float* __restrict__ h1) {
    const int r = blockIdx.x;
    const int j = threadIdx.x;
    const int lo = rel_off[r], hi = rel_off[r + 1];
    const int n = hi - lo;
    const int chunk = (n + C1 - 1) / C1;
    int p = lo + (int)blockIdx.y * chunk;
    const int pend = min(p + chunk, hi);
    if (p >= pend) return;

    float w[EMB];
#pragma unroll
    for (int f = 0; f < EMB; ++f) w[f] = W1[(size_t)r * EMB * HID + f * HID + j];

    // prefetch first edge
    int e = perm[p];
    int d = dst[e];
    const float4* xp = (const float4*)(x + (size_t)src[e] * EMB);
    float4 x0 = xp[0], x1 = xp[1], x2 = xp[2], x3 = xp[3];
    float iv = inv[d * N_REL + r];

    while (p < pend) {
        float4 c0 = x0, c1 = x1, c2 = x2, c3 = x3;
        float civ = iv;
        int cd = d;
        if (p + 1 < pend) {
            int e2 = perm[p + 1];
            d = dst[e2];
            const float4* xp2 = (const float4*)(x + (size_t)src[e2] * EMB);
            x0 = xp2[0]; x1 = xp2[1]; x2 = xp2[2]; x3 = xp2[3];
            iv = inv[d * N_REL + r];
        }
        float acc = c0.x * w[0]  + c0.y * w[1]  + c0.z * w[2]  + c0.w * w[3]
                  + c1.x * w[4]  + c1.y * w[5]  + c1.z * w[6]  + c1.w * w[7]
                  + c2.x * w[8]  + c2.y * w[9]  + c2.z * w[10] + c2.w * w[11]
                  + c3.x * w[12] + c3.y * w[13] + c3.z * w[14] + c3.w * w[15];
        atomicAdd(&h1[(size_t)cd * HID + j], acc * civ);
        ++p;
    }
}

// ---- Layer 2 init: out = b2 + relu(h1) @ root2, node-chunked, weights in regs ----
__global__ __launch_bounds__(128, 3) void l2_init_k(
    const float* __restrict__ h1, const float* __restrict__ root2,
    const float* __restrict__ b2, float* __restrict__ out) {
    __shared__ float hs[2][HID];
    const int j = threadIdx.x;
    float w[HID];
#pragma unroll
    for (int k = 0; k < HID; ++k) w[k] = root2[k * HID + j];
    float bj = b2[j];

    const int per = (N_NODES + gridDim.x - 1) / gridDim.x;
    int n = blockIdx.x * per;
    const int nend = min(n + per, N_NODES);
    if (n >= nend) return;

    float v = h1[(size_t)n * HID + j];
    int buf = 0;
    while (n < nend) {
        hs[buf][j] = fmaxf(v, 0.0f);
        __syncthreads();
        if (n + 1 < nend) v = h1[(size_t)(n + 1) * HID + j];
        const float4* hb = (const float4*)hs[buf];
        float a0 = 0.f, a1 = 0.f, a2 = 0.f, a3 = 0.f;
#pragma unroll
        for (int q = 0; q < 32; ++q) {
            float4 h4 = hb[q];
            a0 += h4.x * w[4 * q + 0];
            a1 += h4.y * w[4 * q + 1];
            a2 += h4.z * w[4 * q + 2];
            a3 += h4.w * w[4 * q + 3];
        }
        out[(size_t)n * HID + j] = (a0 + a1) + (a2 + a3) + bj;
        buf ^= 1;
        ++n;
    }
}

// ---- Layer 2 edges: relation-chunked, W2 column in 128 registers ----
__global__ __launch_bounds__(128, 3) void l2_rel_k(
    const int* __restrict__ perm, const int* __restrict__ rel_off,
    const int* __restrict__ src, const int* __restrict__ dst,
    const float* __restrict__ inv, const float* __restrict__ h1,
    const float* __restrict__ W2, float* __restrict__ out) {
    __shared__ float hs[2][HID];
    const int r = blockIdx.x;
    const int j = threadIdx.x;
    const int lo = rel_off[r], hi = rel_off[r + 1];
    const int n = hi - lo;
    const int chunk = (n + C2 - 1) / C2;
    int p = lo + (int)blockIdx.y * chunk;
    const int pend = min(p + chunk, hi);
    if (p >= pend) return;

    float w[HID];
#pragma unroll
    for (int k = 0; k < HID; ++k) w[k] = W2[(size_t)r * HID * HID + k * HID + j];

    // prefetch first edge
    int e = perm[p];
    int d = dst[e];
    float v = h1[(size_t)src[e] * HID + j];
    float iv = inv[d * N_REL + r];

    int buf = 0;
    while (p < pend) {
        hs[buf][j] = fmaxf(v, 0.0f);
        float civ = iv;
        int cd = d;
        __syncthreads();
        if (p + 1 < pend) {  // prefetch next edge during compute
            int e2 = perm[p + 1];
            d = dst[e2];
            v = h1[(size_t)src[e2] * HID + j];
            iv = inv[d * N_REL + r];
        }
        const float4* hb = (const float4*)hs[buf];
        float a0 = 0.f, a1 = 0.f, a2 = 0.f, a3 = 0.f;
#pragma unroll
        for (int q = 0; q < 32; ++q) {
            float4 h4 = hb[q];
            a0 += h4.x * w[4 * q + 0];
            a1 += h4.y * w[4 * q + 1];
            a2 += h4.z * w[4 * q + 2];
            a3 += h4.w * w[4 * q + 3];
        }
        atomicAdd(&out[(size_t)cd * HID + j], ((a0 + a1) + (a2 + a3)) * civ);
        buf ^= 1;
        ++p;
    }
}

extern "C" void kernel_launch(void* const* d_in, const int* in_sizes, int n_in,
                              void* d_out, int out_size, void* d_ws, size_t ws_size,
                              hipStream_t stream) {
    const int*   ei    = (const int*)d_in[0];   // [2, E]
    const int*   et    = (const int*)d_in[1];   // [E]
    const float* x     = (const float*)d_in[2]; // [N, 16]
    const float* W1    = (const float*)d_in[3]; // [32, 16, 128]
    const float* root1 = (const float*)d_in[4]; // [16, 128]
    const float* b1    = (const float*)d_in[5]; // [128]
    const float* W2    = (const float*)d_in[6]; // [32, 128, 128]
    const float* root2 = (const float*)d_in[7]; // [128, 128]
    const float* b2    = (const float*)d_in[8]; // [128]
    float* out = (float*)d_out;

    // workspace layout
    float* counts    = (float*)d_ws;                       // N*R floats (becomes inv)
    float* h1        = counts + (size_t)N_NODES * N_REL;   // N*HID floats
    int*   perm      = (int*)(h1 + (size_t)N_NODES * HID); // E ints
    int*   rel_count = perm + N_EDGES;                     // 32
    int*   rel_off   = rel_count + N_REL;                  // 33
    int*   cursors   = rel_off + N_REL + 1;                // 32

    const int* src = ei;
    const int* dst = ei + N_EDGES;

    hipMemsetAsync(counts, 0, (size_t)N_NODES * N_REL * sizeof(float), stream);
    hipMemsetAsync(rel_count, 0, N_REL * sizeof(int), stream);

    count_k<<<(N_EDGES + 255) / 256, 256, 0, stream>>>(dst, et, counts, rel_count);
    inv_k<<<(N_NODES * N_REL + 255) / 256, 256, 0, stream>>>(counts);
    scan_k<<<1, 64, 0, stream>>>(rel_count, rel_off, cursors);
    scatter_k<<<(N_EDGES + 255) / 256, 256, 0, stream>>>(et, cursors, perm);

    // layer 1
    l1_init_k<<<(N_NODES * HID + 255) / 256, 256, 0, stream>>>(x, root1, b1, h1);
    l1_rel_k<<<dim3(N_REL, C1), 128, 0, stream>>>(perm, rel_off, src, dst, counts, x, W1, h1);

    // layer 2
    l2_init_k<<<1024, 128, 0, stream>>>(h1, root2, b2, out);
    l2_rel_k<<<dim3(N_REL, C2), 128, 0, stream>>>(perm, rel_off, src, dst, counts, h1, W2, out);
}

// Round 3
// 734.761 us; speedup vs baseline: 2.4622x; 1.4749x over previous
//
#include <hip/hip_runtime.h>
#include <hip/hip_bf16.h>

#define N_NODES 20000
#define N_REL 32
#define HID 128
#define EMB 16
#define N_EDGES 600000
#define CH_EDGE 32   // chunks per relation for edge MFMA kernels

typedef __attribute__((ext_vector_type(8))) short  bf8v;   // 8 bf16 = 4 VGPRs (MFMA A/B frag)
typedef __attribute__((ext_vector_type(4))) unsigned short us4v; // 8-byte LDS/global unit
typedef __attribute__((ext_vector_type(4))) float  f4v;    // MFMA C/D frag

union ABu { bf8v v; us4v h[2]; };

__device__ __forceinline__ unsigned short f2b(float f) {
    __hip_bfloat16 h = __float2bfloat16(f);
    return __builtin_bit_cast(unsigned short, h);
}

// ---- Phase 0a: per-(dst,relation) counts + per-relation histogram ----
__global__ void count_k(const int* __restrict__ dst, const int* __restrict__ et,
                        float* __restrict__ counts, int* __restrict__ rel_count) {
    __shared__ int lh[N_REL];
    int t = threadIdx.x;
    if (t < N_REL) lh[t] = 0;
    __syncthreads();
    int e = blockIdx.x * 256 + t;
    if (e < N_EDGES) {
        int r = et[e];
        atomicAdd(&counts[dst[e] * N_REL + r], 1.0f);
        atomicAdd(&lh[r], 1);
    }
    __syncthreads();
    if (t < N_REL && lh[t] > 0) atomicAdd(&rel_count[t], lh[t]);
}

__global__ void inv_k(float* __restrict__ counts) {
    int i = blockIdx.x * 256 + threadIdx.x;
    if (i < N_NODES * N_REL) {
        float c = counts[i];
        counts[i] = c > 0.0f ? 1.0f / c : 0.0f;
    }
}

__global__ void scan_k(const int* __restrict__ rel_count, int* __restrict__ rel_off,
                       int* __restrict__ cursors) {
    if (threadIdx.x == 0) {
        int s = 0;
        for (int r = 0; r < N_REL; ++r) { rel_off[r] = s; cursors[r] = s; s += rel_count[r]; }
        rel_off[N_REL] = s;
    }
}

__global__ void scatter_k(const int* __restrict__ et, int* __restrict__ cursors,
                          int* __restrict__ perm) {
    __shared__ int lh[N_REL];
    __shared__ int lbase[N_REL];
    int t = threadIdx.x;
    if (t < N_REL) lh[t] = 0;
    __syncthreads();
    int e = blockIdx.x * 256 + t;
    int r = -1, my = 0;
    if (e < N_EDGES) { r = et[e]; my = atomicAdd(&lh[r], 1); }
    __syncthreads();
    if (t < N_REL && lh[t] > 0) lbase[t] = atomicAdd(&cursors[t], lh[t]);
    __syncthreads();
    if (e < N_EDGES) perm[lbase[r] + my] = e;
}

// ---- Layer 1 init: h1 = b1 + x @ root1 (fp32 VALU, K=16, cheap) ----
__global__ void l1_init_k(const float* __restrict__ x, const float* __restrict__ root1,
                          const float* __restrict__ b1, float* __restrict__ h1) {
    int idx = blockIdx.x * 256 + threadIdx.x;
    if (idx >= N_NODES * HID) return;
    int n = idx >> 7, j = idx & 127;
    float acc = b1[j];
    const float* xs = x + n * EMB;
#pragma unroll
    for (int f = 0; f < EMB; ++f) acc += xs[f] * root1[f * HID + j];
    h1[idx] = acc;
}

// ---- bf16 conversion / transpose kernels ----
__global__ void conv_x_k(const float* __restrict__ x, unsigned short* __restrict__ xb) {
    int i = blockIdx.x * 256 + threadIdx.x;
    if (i >= N_NODES * 32) return;
    int n = i >> 5, k = i & 31;
    xb[i] = (k < EMB) ? f2b(x[n * EMB + k]) : (unsigned short)0;
}
__global__ void conv_w1_k(const float* __restrict__ W1, unsigned short* __restrict__ w1t) {
    int i = blockIdx.x * 256 + threadIdx.x;
    if (i >= N_REL * HID * 32) return;
    int r = i >> 12, n = (i >> 5) & 127, k = i & 31;
    w1t[i] = (k < EMB) ? f2b(W1[r * EMB * HID + k * HID + n]) : (unsigned short)0;
}
__global__ void conv_w2_k(const float* __restrict__ W2, unsigned short* __restrict__ w2t) {
    int i = blockIdx.x * 256 + threadIdx.x;
    if (i >= N_REL * HID * HID) return;
    int r = i >> 14, n = (i >> 7) & 127, k = i & 127;
    w2t[i] = f2b(W2[r * HID * HID + k * HID + n]);
}
__global__ void conv_r2_k(const float* __restrict__ root2, unsigned short* __restrict__ r2t) {
    int i = blockIdx.x * 256 + threadIdx.x;
    if (i >= HID * HID) return;
    int n = i >> 7, k = i & 127;
    r2t[i] = f2b(root2[k * HID + n]);
}
__global__ void conv_h_k(const float* __restrict__ h1, unsigned short* __restrict__ h1b) {
    int i = blockIdx.x * 256 + threadIdx.x;
    if (i >= N_NODES * HID) return;
    h1b[i] = f2b(fmaxf(h1[i], 0.0f));
}

// ---- Unified MFMA GEMM kernel ----
// EDGE=true : per-relation edge GEMM with gather(src)/scatter-atomic(dst)*inv
//             grid = (N_REL, CH_EDGE), out += (A[src] @ B[r]) * inv
// EDGE=false: root GEMM over nodes, grid = (N_NODES/32, 1), out = A @ B + bias
// KT = K/32 tiles; ROWB16 = row length in bf16 (=KT*32); LS = padded LDS row stride (bf16)
template<int KT, int LS, int ROWB16, bool EDGE>
__global__ __launch_bounds__(256) void mfma_k(
    const int* __restrict__ perm, const int* __restrict__ rel_off,
    const int* __restrict__ src, const int* __restrict__ dstp,
    const float* __restrict__ inv,
    const unsigned short* __restrict__ Aa,   // bf16 rows [*, ROWB16]
    const unsigned short* __restrict__ Bb,   // bf16 B^T [r][128][ROWB16]
    const float* __restrict__ bias,
    float* __restrict__ out) {

    __shared__ unsigned short As[32 * LS];
    __shared__ int   srn[32];
    __shared__ int   dn[32];
    __shared__ float cv[32];

    const int t = threadIdx.x;
    const int wave = t >> 6, lane = t & 63;
    const int q = lane >> 4, m16 = lane & 15;

    int r = 0, lo = 0, hi = 0, t0, t1;
    if constexpr (EDGE) {
        r = blockIdx.x;
        lo = rel_off[r]; hi = rel_off[r + 1];
        const int ntiles = (hi - lo + 31) >> 5;
        const int tpc = (ntiles + (int)gridDim.y - 1) / (int)gridDim.y;
        t0 = (int)blockIdx.y * tpc;
        t1 = min(t0 + tpc, ntiles);
        if (t0 >= t1) return;
    } else {
        t0 = blockIdx.x; t1 = t0 + 1;
    }

    // B fragments: wave covers col-tiles 2*wave, 2*wave+1 (cols 32*wave .. +32)
    bf8v bf[2][KT];
#pragma unroll
    for (int ct = 0; ct < 2; ++ct) {
        const int n = m16 + 16 * (2 * wave + ct);
#pragma unroll
        for (int ks = 0; ks < KT; ++ks)
            bf[ct][ks] = *(const bf8v*)(Bb + ((size_t)r * HID + n) * ROWB16 + ks * 32 + q * 8);
    }

    constexpr int CH8 = ROWB16 / 4;   // ushort4 (8B) chunks per row

    for (int tt = t0; tt < t1; ++tt) {
        const int p0 = (EDGE ? lo : 0) + tt * 32;
        __syncthreads();   // protect LDS (As/meta) against previous iter readers
        if constexpr (EDGE) {
            if (t < 32) {
                int p = p0 + t;
                if (p < hi) {
                    int e = perm[p];
                    srn[t] = src[e];
                    int d = dstp[e];
                    dn[t] = d;
                    cv[t] = inv[d * N_REL + r];
                } else {
                    srn[t] = src[perm[lo]];
                    dn[t] = 0;
                    cv[t] = 0.0f;
                }
            }
            __syncthreads();
        }
        // gather 32 A-rows into LDS
#pragma unroll
        for (int c = t; c < 32 * CH8; c += 256) {
            int row = c / CH8, sub = c % CH8;
            int srow = EDGE ? srn[row] : (p0 + row);
            *(us4v*)(&As[row * LS + sub * 4]) =
                *(const us4v*)(Aa + (size_t)srow * ROWB16 + sub * 4);
        }
        __syncthreads();

        // A fragments
        bf8v af[2][KT];
#pragma unroll
        for (int rt = 0; rt < 2; ++rt)
#pragma unroll
            for (int ks = 0; ks < KT; ++ks) {
                const unsigned short* ap = &As[(m16 + 16 * rt) * LS + ks * 32 + q * 8];
                ABu u;
                u.h[0] = *(const us4v*)(ap);
                u.h[1] = *(const us4v*)(ap + 4);
                af[rt][ks] = u.v;
            }

        // MFMA + epilogue
#pragma unroll
        for (int rt = 0; rt < 2; ++rt) {
#pragma unroll
            for (int ct = 0; ct < 2; ++ct) {
                f4v acc = {0.f, 0.f, 0.f, 0.f};
#pragma unroll
                for (int ks = 0; ks < KT; ++ks)
                    acc = __builtin_amdgcn_mfma_f32_16x16x32_bf16(af[rt][ks], bf[ct][ks], acc, 0, 0, 0);
                const int col = m16 + 16 * (2 * wave + ct);
#pragma unroll
                for (int g = 0; g < 4; ++g) {
                    const int rr = q * 4 + g + 16 * rt;   // C/D: row = quad*4+reg (+rowtile)
                    if constexpr (EDGE) {
                        atomicAdd(&out[(size_t)dn[rr] * HID + col], acc[g] * cv[rr]);
                    } else {
                        out[(size_t)(p0 + rr) * HID + col] = acc[g] + bias[col];
                    }
                }
            }
        }
    }
}

extern "C" void kernel_launch(void* const* d_in, const int* in_sizes, int n_in,
                              void* d_out, int out_size, void* d_ws, size_t ws_size,
                              hipStream_t stream) {
    const int*   ei    = (const int*)d_in[0];   // [2, E]
    const int*   et    = (const int*)d_in[1];   // [E]
    const float* x     = (const float*)d_in[2]; // [N, 16]
    const float* W1    = (const float*)d_in[3]; // [32, 16, 128]
    const float* root1 = (const float*)d_in[4]; // [16, 128]
    const float* b1    = (const float*)d_in[5]; // [128]
    const float* W2    = (const float*)d_in[6]; // [32, 128, 128]
    const float* root2 = (const float*)d_in[7]; // [128, 128]
    const float* b2    = (const float*)d_in[8]; // [128]
    float* out = (float*)d_out;

    // ---- workspace layout (byte offsets, 64B-aligned sections) ----
    char* ws = (char*)d_ws;
    size_t off = 0;
    auto alloc = [&](size_t bytes) { void* p = ws + off; off = (off + bytes + 63) & ~(size_t)63; return p; };
    float* counts    = (float*)alloc((size_t)N_NODES * N_REL * 4);   // -> inv
    float* h1        = (float*)alloc((size_t)N_NODES * HID * 4);
    int*   perm      = (int*)  alloc((size_t)N_EDGES * 4);
    int*   rel_count = (int*)  alloc(N_REL * 4);
    int*   rel_off   = (int*)  alloc((N_REL + 1) * 4);
    int*   cursors   = (int*)  alloc(N_REL * 4);
    unsigned short* xb  = (unsigned short*)alloc((size_t)N_NODES * 32 * 2);
    unsigned short* h1b = (unsigned short*)alloc((size_t)N_NODES * HID * 2);
    unsigned short* w1t = (unsigned short*)alloc((size_t)N_REL * HID * 32 * 2);
    unsigned short* w2t = (unsigned short*)alloc((size_t)N_REL * HID * HID * 2);
    unsigned short* r2t = (unsigned short*)alloc((size_t)HID * HID * 2);

    const int* src = ei;
    const int* dst = ei + N_EDGES;

    hipMemsetAsync(counts, 0, (size_t)N_NODES * N_REL * 4, stream);
    hipMemsetAsync(rel_count, 0, N_REL * 4, stream);

    count_k<<<(N_EDGES + 255) / 256, 256, 0, stream>>>(dst, et, counts, rel_count);
    inv_k<<<(N_NODES * N_REL + 255) / 256, 256, 0, stream>>>(counts);
    scan_k<<<1, 64, 0, stream>>>(rel_count, rel_off, cursors);
    scatter_k<<<(N_EDGES + 255) / 256, 256, 0, stream>>>(et, cursors, perm);

    // conversions (independent of edge sort)
    conv_x_k<<<(N_NODES * 32 + 255) / 256, 256, 0, stream>>>(x, xb);
    conv_w1_k<<<(N_REL * HID * 32 + 255) / 256, 256, 0, stream>>>(W1, w1t);
    conv_w2_k<<<(N_REL * HID * HID + 255) / 256, 256, 0, stream>>>(W2, w2t);
    conv_r2_k<<<(HID * HID + 255) / 256, 256, 0, stream>>>(root2, r2t);

    // layer 1
    l1_init_k<<<(N_NODES * HID + 255) / 256, 256, 0, stream>>>(x, root1, b1, h1);
    mfma_k<1, 36, 32, true><<<dim3(N_REL, CH_EDGE), 256, 0, stream>>>(
        perm, rel_off, src, dst, counts, xb, w1t, nullptr, h1);

    // relu + bf16 convert of h1
    conv_h_k<<<(N_NODES * HID + 255) / 256, 256, 0, stream>>>(h1, h1b);

    // layer 2: root GEMM (direct store), then edge GEMM (atomic)
    mfma_k<4, 132, 128, false><<<dim3(N_NODES / 32, 1), 256, 0, stream>>>(
        nullptr, nullptr, nullptr, nullptr, nullptr, h1b, r2t, b2, out);
    mfma_k<4, 132, 128, true><<<dim3(N_REL, CH_EDGE), 256, 0, stream>>>(
        perm, rel_off, src, dst, counts, h1b, w2t, nullptr, out);
}

// Round 4
// 561.702 us; speedup vs baseline: 3.2207x; 1.3081x over previous
//
#include <hip/hip_runtime.h>
#include <hip/hip_bf16.h>

#define N_NODES 20000
#define N_REL 32
#define HID 128
#define EMB 16
#define N_EDGES 600000
#define NB (N_NODES * N_REL)   // 640000 bins

typedef __attribute__((ext_vector_type(8))) short  bf8v;   // 8 bf16 (MFMA A/B frag)
typedef __attribute__((ext_vector_type(4))) unsigned short us4v; // 8-byte unit
typedef __attribute__((ext_vector_type(4))) float  f4v;    // MFMA C/D frag

union ABu { bf8v v; us4v h[2]; };

__device__ __forceinline__ unsigned short f2b(float f) {
    __hip_bfloat16 h = __float2bfloat16(f);
    return __builtin_bit_cast(unsigned short, h);
}
__device__ __forceinline__ float b2f(unsigned short u) {
    unsigned int x = ((unsigned int)u) << 16;
    return __builtin_bit_cast(float, x);
}

// ---- binning: histogram over (dst, rel) bins ----
__global__ void hist_k(const int* __restrict__ dst, const int* __restrict__ et,
                       int* __restrict__ hist) {
    int e = blockIdx.x * 256 + threadIdx.x;
    if (e < N_EDGES) atomicAdd(&hist[dst[e] * N_REL + et[e]], 1);
}

__global__ void inv_k(const int* __restrict__ hist, float* __restrict__ inv) {
    int i = blockIdx.x * 256 + threadIdx.x;
    if (i < NB) {
        int c = hist[i];
        inv[i] = c > 0 ? 1.0f / (float)c : 0.0f;
    }
}

// ---- 2-level exclusive scan over NB=640000 = 625 blocks x 1024 ----
__global__ void scan1_k(const int* __restrict__ hist, int* __restrict__ binoff,
                        int* __restrict__ bsum) {
    __shared__ int sh[256];
    const int t = threadIdx.x;
    const int base = blockIdx.x * 1024 + t * 4;
    int4 h4 = *(const int4*)(hist + base);
    int ts = h4.x + h4.y + h4.z + h4.w;
    sh[t] = ts;
    __syncthreads();
    for (int o = 1; o < 256; o <<= 1) {
        int v = (t >= o) ? sh[t - o] : 0;
        __syncthreads();
        sh[t] += v;
        __syncthreads();
    }
    int exc = sh[t] - ts;
    binoff[base + 0] = exc;
    binoff[base + 1] = exc + h4.x;
    binoff[base + 2] = exc + h4.x + h4.y;
    binoff[base + 3] = exc + h4.x + h4.y + h4.z;
    if (t == 255) bsum[blockIdx.x] = sh[255];
}

__global__ void scan2_k(const int* __restrict__ bsum, int* __restrict__ bbase) {
    __shared__ int sh[1024];
    const int t = threadIdx.x;
    int v = (t < 625) ? bsum[t] : 0;
    sh[t] = v;
    __syncthreads();
    for (int o = 1; o < 1024; o <<= 1) {
        int u = (t >= o) ? sh[t - o] : 0;
        __syncthreads();
        sh[t] += u;
        __syncthreads();
    }
    if (t < 625) bbase[t] = sh[t] - v;
}

__global__ void scan3_k(int* __restrict__ binoff, const int* __restrict__ bbase,
                        int* __restrict__ cursors) {
    int i = blockIdx.x * 256 + threadIdx.x;
    if (i < NB) {
        int v = binoff[i] + bbase[i >> 10];
        binoff[i] = v;
        cursors[i] = v;
    }
    if (i == 0) binoff[NB] = N_EDGES;
}

__global__ void scatter_k(const int* __restrict__ src, const int* __restrict__ dst,
                          const int* __restrict__ et, int* __restrict__ cursors,
                          int* __restrict__ ssrc) {
    int e = blockIdx.x * 256 + threadIdx.x;
    if (e < N_EDGES) {
        int b = dst[e] * N_REL + et[e];
        int p = atomicAdd(&cursors[b], 1);
        ssrc[p] = src[e];
    }
}

// ---- bf16 conversion / transpose kernels ----
__global__ void conv_x_k(const float* __restrict__ x, unsigned short* __restrict__ xb) {
    int i = blockIdx.x * 256 + threadIdx.x;
    if (i >= N_NODES * 32) return;
    int n = i >> 5, k = i & 31;
    xb[i] = (k < EMB) ? f2b(x[n * EMB + k]) : (unsigned short)0;
}
__global__ void conv_w1_k(const float* __restrict__ W1, unsigned short* __restrict__ w1t) {
    int i = blockIdx.x * 256 + threadIdx.x;
    if (i >= N_REL * HID * 32) return;
    int r = i >> 12, n = (i >> 5) & 127, k = i & 31;
    w1t[i] = (k < EMB) ? f2b(W1[r * EMB * HID + k * HID + n]) : (unsigned short)0;
}
__global__ void conv_r1_k(const float* __restrict__ root1, unsigned short* __restrict__ r1t) {
    int i = blockIdx.x * 256 + threadIdx.x;
    if (i >= HID * 32) return;
    int n = i >> 5, k = i & 31;
    r1t[i] = (k < EMB) ? f2b(root1[k * HID + n]) : (unsigned short)0;
}
__global__ void conv_w2_k(const float* __restrict__ W2, unsigned short* __restrict__ w2t) {
    int i = blockIdx.x * 256 + threadIdx.x;
    if (i >= N_REL * HID * HID) return;
    int r = i >> 14, n = (i >> 7) & 127, k = i & 127;
    w2t[i] = f2b(W2[r * HID * HID + k * HID + n]);
}
__global__ void conv_r2_k(const float* __restrict__ root2, unsigned short* __restrict__ r2t) {
    int i = blockIdx.x * 256 + threadIdx.x;
    if (i >= HID * HID) return;
    int n = i >> 7, k = i & 127;
    r2t[i] = f2b(root2[k * HID + n]);
}

// ---- fused aggregate-then-transform GEMM (no atomics) ----
// Block: 32 dst nodes x 64 cols (2 waves x 32 cols). grid = (625, 2).
// Iter r=0..31: A[row] = inv[b] * sum_{e in bin b=(d0+row)*32+r} G[ssrc[e]]  (bf16, LDS)
//               acc += A @ Bw[r]^T   (MFMA 16x16x32 bf16)
// Iter 32:      A[row] = G[d0+row]; acc += A @ Br^T   (root transform)
// Epilogue:     L1: h1b = bf16(relu(acc + bias)); else: out = acc + bias (fp32)
template<int KT, int LS, bool L1>
__global__ __launch_bounds__(128) void gemm_k(
    const int* __restrict__ binoff, const float* __restrict__ inv,
    const int* __restrict__ ssrc,
    const unsigned short* __restrict__ G,    // bf16 rows [*, KT*32]
    const unsigned short* __restrict__ Bw,   // bf16 W^T [r][128][KT*32]
    const unsigned short* __restrict__ Br,   // bf16 root^T [128][KT*32]
    const float* __restrict__ bias,
    void* __restrict__ outp) {

    constexpr int ROW = KT * 32;   // bf16 per A-row
    constexpr int CH  = ROW / 4;   // us4v chunks per row

    __shared__ unsigned short As[32 * LS];
    __shared__ int   soff[2][32];
    __shared__ int   eoff[2][32];
    __shared__ float sinv[2][32];

    const int t = threadIdx.x;
    const int w = t >> 6, lane = t & 63;
    const int q = lane >> 4, m16 = lane & 15;
    const int d0 = blockIdx.x * 32;
    const int colb = blockIdx.y * 64 + w * 32;   // this wave's column base

    f4v acc[2][2];
#pragma unroll
    for (int rt = 0; rt < 2; ++rt)
#pragma unroll
        for (int ct = 0; ct < 2; ++ct) acc[rt][ct] = f4v{0.f, 0.f, 0.f, 0.f};

    for (int it = 0; it <= N_REL; ++it) {
        const int buf = it & 1;
        if (it < N_REL && t < 32) {
            int b = (d0 + t) * N_REL + it;
            soff[buf][t] = binoff[b];
            eoff[buf][t] = binoff[b + 1];
            sinv[buf][t] = inv[b];
        }
        // B fragments for this iteration (global, L2-resident)
        const unsigned short* Bp = (it < N_REL) ? (Bw + (size_t)it * HID * ROW) : Br;
        bf8v bf[2][KT];
#pragma unroll
        for (int ct = 0; ct < 2; ++ct) {
            const int n = colb + 16 * ct + m16;
#pragma unroll
            for (int ks = 0; ks < KT; ++ks)
                bf[ct][ks] = *(const bf8v*)(Bp + (size_t)n * ROW + ks * 32 + q * 8);
        }
        __syncthreads();   // prev iter's A-frag reads done; meta visible

        // build A tile in LDS
        if (it < N_REL) {
#pragma unroll
            for (int u = t; u < 32 * CH; u += 128) {
                const int row = u / CH, c4 = u % CH;
                const int so = soff[buf][row], eo = eoff[buf][row];
                float a0 = 0.f, a1 = 0.f, a2 = 0.f, a3 = 0.f;
                for (int p = so; p < eo; ++p) {
                    const int s = ssrc[p];
                    us4v hv = *(const us4v*)(G + (size_t)s * ROW + c4 * 4);
                    a0 += b2f(hv[0]); a1 += b2f(hv[1]);
                    a2 += b2f(hv[2]); a3 += b2f(hv[3]);
                }
                const float iv = sinv[buf][row];
                us4v sv = { f2b(a0 * iv), f2b(a1 * iv), f2b(a2 * iv), f2b(a3 * iv) };
                *(us4v*)(&As[row * LS + c4 * 4]) = sv;
            }
        } else {
#pragma unroll
            for (int u = t; u < 32 * CH; u += 128) {
                const int row = u / CH, c4 = u % CH;
                *(us4v*)(&As[row * LS + c4 * 4]) =
                    *(const us4v*)(G + (size_t)(d0 + row) * ROW + c4 * 4);
            }
        }
        __syncthreads();   // A visible

        // A fragments + MFMA
#pragma unroll
        for (int rt = 0; rt < 2; ++rt) {
#pragma unroll
            for (int ks = 0; ks < KT; ++ks) {
                const unsigned short* ap = &As[(m16 + 16 * rt) * LS + ks * 32 + q * 8];
                ABu u;
                u.h[0] = *(const us4v*)(ap);
                u.h[1] = *(const us4v*)(ap + 4);
#pragma unroll
                for (int ct = 0; ct < 2; ++ct)
                    acc[rt][ct] = __builtin_amdgcn_mfma_f32_16x16x32_bf16(u.v, bf[ct][ks], acc[rt][ct], 0, 0, 0);
            }
        }
    }

    // epilogue: direct stores, no atomics
#pragma unroll
    for (int ct = 0; ct < 2; ++ct) {
        const int col = colb + 16 * ct + m16;
        const float bc = bias[col];
#pragma unroll
        for (int rt = 0; rt < 2; ++rt) {
#pragma unroll
            for (int g = 0; g < 4; ++g) {
                const int rr = 16 * rt + q * 4 + g;
                if constexpr (L1) {
                    ((unsigned short*)outp)[(size_t)(d0 + rr) * HID + col] =
                        f2b(fmaxf(acc[rt][ct][g] + bc, 0.0f));
                } else {
                    ((float*)outp)[(size_t)(d0 + rr) * HID + col] = acc[rt][ct][g] + bc;
                }
            }
        }
    }
}

extern "C" void kernel_launch(void* const* d_in, const int* in_sizes, int n_in,
                              void* d_out, int out_size, void* d_ws, size_t ws_size,
                              hipStream_t stream) {
    const int*   ei    = (const int*)d_in[0];   // [2, E]
    const int*   et    = (const int*)d_in[1];   // [E]
    const float* x     = (const float*)d_in[2]; // [N, 16]
    const float* W1    = (const float*)d_in[3]; // [32, 16, 128]
    const float* root1 = (const float*)d_in[4]; // [16, 128]
    const float* b1    = (const float*)d_in[5]; // [128]
    const float* W2    = (const float*)d_in[6]; // [32, 128, 128]
    const float* root2 = (const float*)d_in[7]; // [128, 128]
    const float* b2    = (const float*)d_in[8]; // [128]
    float* out = (float*)d_out;

    // ---- workspace layout ----
    char* ws = (char*)d_ws;
    size_t off = 0;
    auto alloc = [&](size_t bytes) { void* p = ws + off; off = (off + bytes + 63) & ~(size_t)63; return p; };
    int*   hist    = (int*)  alloc((size_t)NB * 4);
    int*   binoff  = (int*)  alloc((size_t)(NB + 1) * 4);
    int*   cursors = (int*)  alloc((size_t)NB * 4);
    float* inv     = (float*)alloc((size_t)NB * 4);
    int*   bsum    = (int*)  alloc(625 * 4);
    int*   bbase   = (int*)  alloc(625 * 4);
    int*   ssrc    = (int*)  alloc((size_t)N_EDGES * 4);
    unsigned short* xb  = (unsigned short*)alloc((size_t)N_NODES * 32 * 2);
    unsigned short* h1b = (unsigned short*)alloc((size_t)N_NODES * HID * 2);
    unsigned short* w1t = (unsigned short*)alloc((size_t)N_REL * HID * 32 * 2);
    unsigned short* r1t = (unsigned short*)alloc((size_t)HID * 32 * 2);
    unsigned short* w2t = (unsigned short*)alloc((size_t)N_REL * HID * HID * 2);
    unsigned short* r2t = (unsigned short*)alloc((size_t)HID * HID * 2);

    const int* src = ei;
    const int* dst = ei + N_EDGES;

    hipMemsetAsync(hist, 0, (size_t)NB * 4, stream);

    // binning
    hist_k<<<(N_EDGES + 255) / 256, 256, 0, stream>>>(dst, et, hist);
    inv_k<<<(NB + 255) / 256, 256, 0, stream>>>(hist, inv);
    scan1_k<<<NB / 1024, 256, 0, stream>>>(hist, binoff, bsum);
    scan2_k<<<1, 1024, 0, stream>>>(bsum, bbase);
    scan3_k<<<(NB + 255) / 256, 256, 0, stream>>>(binoff, bbase, cursors);
    scatter_k<<<(N_EDGES + 255) / 256, 256, 0, stream>>>(src, dst, et, cursors, ssrc);

    // bf16 conversions
    conv_x_k<<<(N_NODES * 32 + 255) / 256, 256, 0, stream>>>(x, xb);
    conv_w1_k<<<(N_REL * HID * 32 + 255) / 256, 256, 0, stream>>>(W1, w1t);
    conv_r1_k<<<(HID * 32 + 255) / 256, 256, 0, stream>>>(root1, r1t);
    conv_w2_k<<<(N_REL * HID * HID + 255) / 256, 256, 0, stream>>>(W2, w2t);
    conv_r2_k<<<(HID * HID + 255) / 256, 256, 0, stream>>>(root2, r2t);

    // layer 1: writes h1b = bf16(relu(.)) directly
    gemm_k<1, 36, true><<<dim3(N_NODES / 32, 2), 128, 0, stream>>>(
        binoff, inv, ssrc, xb, w1t, r1t, b1, h1b);

    // layer 2: writes out fp32
    gemm_k<4, 132, false><<<dim3(N_NODES / 32, 2), 128, 0, stream>>>(
        binoff, inv, ssrc, h1b, w2t, r2t, b2, out);
}